// Round 5
// baseline (377.210 us; speedup 1.0000x reference)
//
#include <hip/hip_runtime.h>
#include <stdint.h>
#include <float.h>
#include <limits.h>

// ---------------------------------------------------------------------------
// Sampler: logits = (h @ E^T + bias) / T; softmax; top-p/top-k mask;
// jax.random.categorical(key(42)) == argmax(logp + gumbel) over kept set.
// GEMM via bf16 MFMA, 3-term split (loA*hiB + hiA*loB + hiA*hiB), k-ascending
// per accumulator (bit-identical order to the verified round-3/4 kernel).
// Round 5: LDS-free streaming GEMM. Each wave = 64(batch) x 32(vocab),
// B loaded per-lane in fragment order from global (4-deep reg circular
// buffer, 3 tiles prefetch ahead), A pre-split frag-ordered in L2 (1 tile
// ahead). No barriers -> pure TLP/ILP latency hiding.
// ---------------------------------------------------------------------------

typedef __bf16 bf16x8 __attribute__((ext_vector_type(8)));
typedef float  f32x4  __attribute__((ext_vector_type(4)));

// pack 8 floats -> hi bf16 (RNE) + lo bf16 (RNE of residual)
__device__ __forceinline__ void split8v(const float* f, bf16x8& hi, bf16x8& lo) {
#pragma unroll
    for (int e = 0; e < 8; ++e) {
        const __bf16 h = (__bf16)f[e];
        hi[e] = h;
        lo[e] = (__bf16)(f[e] - (float)h);
    }
}
__device__ __forceinline__ void split8(const float* f, uint4& hi, uint4& lo) {
    bf16x8 vh, vl;
    split8v(f, vh, vl);
    hi = __builtin_bit_cast(uint4, vh);
    lo = __builtin_bit_cast(uint4, vl);
}

// ---------------------------------------------------------------------------
// prep: h[b, pos, :] -> A_hi/A_lo in MFMA fragment order (verified layout):
// idx = ((r16*128 + kc)*64 + lh*16 + ll)*8 + j ; row = r16*16+ll,
// k = kc*32 + lh*8 + j.
// ---------------------------------------------------------------------------
__global__ __launch_bounds__(256) void prep_h(
    const float* __restrict__ hs, const int* __restrict__ pos_p,
    unsigned short* __restrict__ Ahi, unsigned short* __restrict__ Alo,
    int H, int L)
{
    const int pos = pos_p[0];
    const int tid = blockIdx.x * 256 + threadIdx.x;   // B*H/16 threads
    const int b     = tid >> 8;                       // 0..63
    const int kbase = (tid & 255) * 16;               // 0..4080
    const float* src = hs + ((size_t)b * L + pos) * H + kbase;
    float f[16];
    *(float4*)&f[0]  = *(const float4*)(src);
    *(float4*)&f[4]  = *(const float4*)(src + 4);
    *(float4*)&f[8]  = *(const float4*)(src + 8);
    *(float4*)&f[12] = *(const float4*)(src + 12);

    const int r16 = b >> 4, ll = b & 15;
    const int kc  = kbase >> 5;
    const int lh0 = (kbase >> 3) & 3;
#pragma unroll
    for (int c = 0; c < 2; ++c) {
        uint4 hi, lo;
        split8(f + 8 * c, hi, lo);
        const size_t dst = ((size_t)(r16 * 128 + kc) * 64 + (lh0 + c) * 16 + ll) * 8;
        *(uint4*)&Ahi[dst] = hi;
        *(uint4*)&Alo[dst] = lo;
    }
}

// ---------------------------------------------------------------------------
// GEMM: grid of ceil(V/128) blocks x 256 threads; wave w owns vocab strip
// [v0 + 32*w, +32) x all 64 batch rows. 16x16x32 bf16 MFMA.
// ---------------------------------------------------------------------------
__global__ __launch_bounds__(256) void logits_mfma(
    const float* __restrict__ emb,              // [V][H] fp32
    const unsigned short* __restrict__ Ahi,     // frag-ordered bf16
    const unsigned short* __restrict__ Alo,
    const float* __restrict__ temps,            // [B]
    const float* __restrict__ bias,             // [V]
    float*       __restrict__ out,              // [B][V] scaled logits
    int V, int H)
{
    const int tid  = threadIdx.x;
    const int lane = tid & 63;
    const int w    = tid >> 6;
    const int wv0  = blockIdx.x * 128 + w * 32;

    const int ll = lane & 15;        // frag col (vocab) / row (batch)
    const int lh = lane >> 4;        // k sub-chunk

    const int NKC = H >> 5;          // 32-wide K tiles (128)

    // B per-lane row pointers (rows clamped; stores guarded later)
    const float* bptr[2];
#pragma unroll
    for (int n = 0; n < 2; ++n) {
        int r = wv0 + 16 * n + ll;
        r = (r < V) ? r : (V - 1);
        bptr[n] = emb + (size_t)r * H + lh * 8;
    }

    // A fragment base offsets (elements): i = r16 block 0..3
    const size_t aoff = (size_t)lh * 128 + (size_t)ll * 8;

    float4 rb[4][4];                 // 4-tile circular buffer of raw B fp32
    bf16x8 aih[2][4], ail[2][4];     // A frags, 2-tile parity buffer
    f32x4  acc[4][2];
#pragma unroll
    for (int i = 0; i < 4; ++i)
#pragma unroll
        for (int j = 0; j < 2; ++j)
            acc[i][j] = (f32x4){0.f, 0.f, 0.f, 0.f};

#define LOADB(t, bi) do {                                                     \
    if ((t) < NKC) {                                                          \
        _Pragma("unroll")                                                     \
        for (int n = 0; n < 2; ++n) {                                         \
            _Pragma("unroll")                                                 \
            for (int q = 0; q < 2; ++q)                                       \
                rb[bi][n * 2 + q] =                                           \
                    *(const float4*)(bptr[n] + (size_t)(t) * 32 + q * 4);     \
        }                                                                     \
    }                                                                         \
} while (0)

#define LOADA(t, p) do {                                                      \
    if ((t) < NKC) {                                                          \
        _Pragma("unroll")                                                     \
        for (int i = 0; i < 4; ++i) {                                         \
            const size_t ai = aoff + (size_t)i * 65536 + (size_t)(t) * 512;   \
            aih[p][i] = *(const bf16x8*)&Ahi[ai];                             \
            ail[p][i] = *(const bf16x8*)&Alo[ai];                             \
        }                                                                     \
    }                                                                         \
} while (0)

#define COMPUTE(bi, p) do {                                                   \
    bf16x8 fbh[2], fbl[2];                                                    \
    _Pragma("unroll")                                                         \
    for (int n = 0; n < 2; ++n) {                                             \
        float f[8];                                                           \
        *(float4*)&f[0] = rb[bi][2 * n];                                      \
        *(float4*)&f[4] = rb[bi][2 * n + 1];                                  \
        split8v(f, fbh[n], fbl[n]);                                           \
    }                                                                         \
    _Pragma("unroll")                                                         \
    for (int j = 0; j < 2; ++j)                                               \
        _Pragma("unroll")                                                     \
        for (int i = 0; i < 4; ++i) {                                         \
            acc[i][j] = __builtin_amdgcn_mfma_f32_16x16x32_bf16(              \
                ail[p][i], fbh[j], acc[i][j], 0, 0, 0);                       \
            acc[i][j] = __builtin_amdgcn_mfma_f32_16x16x32_bf16(              \
                aih[p][i], fbl[j], acc[i][j], 0, 0, 0);                       \
            acc[i][j] = __builtin_amdgcn_mfma_f32_16x16x32_bf16(              \
                aih[p][i], fbh[j], acc[i][j], 0, 0, 0);                       \
        }                                                                     \
} while (0)

    // preload: B tiles 0..2, A tile 0
    LOADA(0, 0);
    LOADB(0, 0);
    LOADB(1, 1);
    LOADB(2, 2);

    for (int kb = 0; kb < NKC; kb += 4) {
        LOADB(kb + 3, 3); LOADA(kb + 1, 1); COMPUTE(0, 0);
        LOADB(kb + 4, 0); LOADA(kb + 2, 0); COMPUTE(1, 1);
        LOADB(kb + 5, 1); LOADA(kb + 3, 1); COMPUTE(2, 0);
        LOADB(kb + 6, 2); LOADA(kb + 4, 0); COMPUTE(3, 1);
    }
#undef LOADB
#undef LOADA
#undef COMPUTE

    // epilogue: C col = lane&15 (vocab), row = (lane>>4)*4 + r (batch)
#pragma unroll
    for (int j = 0; j < 2; ++j) {
        const int vv = wv0 + 16 * j + ll;
        if (vv < V) {
            const float bv = bias[vv];
#pragma unroll
            for (int i = 0; i < 4; ++i)
#pragma unroll
                for (int r = 0; r < 4; ++r) {
                    const int b = 16 * i + lh * 4 + r;
                    out[(size_t)b * V + vv] = (acc[i][j][r] + bv) / temps[b];
                }
        }
    }
}

// ---------------------------------------------------------------------------
// JAX threefry2x32 gumbel — partitionable path (verified round 2).
// ---------------------------------------------------------------------------
__device__ __forceinline__ uint32_t rotl32(uint32_t x, int d) {
    return (x << d) | (x >> (32 - d));
}

__device__ float jax_gumbel(uint32_t flat) {
    const uint32_t k0 = 0u, k1 = 42u;
    const uint32_t ks[3] = { k0, k1, k0 ^ k1 ^ 0x1BD11BDAu };
    uint32_t x0 = 0u   + ks[0];
    uint32_t x1 = flat + ks[1];
    const int rot[2][4] = { {13, 15, 26, 6}, {17, 29, 16, 24} };
#pragma unroll
    for (int r = 0; r < 5; ++r) {
        const int* rr = rot[r & 1];
#pragma unroll
        for (int j = 0; j < 4; ++j) {
            x0 += x1;
            x1 = rotl32(x1, rr[j]);
            x1 ^= x0;
        }
        x0 += ks[(r + 1) % 3];
        x1 += ks[(r + 2) % 3] + (uint32_t)(r + 1);
    }
    const uint32_t bits = x0 ^ x1;
    const uint32_t fb = (bits >> 9) | 0x3F800000u;
    const float f = __uint_as_float(fb) - 1.0f;
    const float tiny = 1.17549435e-38f;
    float u = __fadd_rn(__fmul_rn(f, 1.0f), tiny);
    u = fmaxf(tiny, u);
    const float l1 = logf(u);
    return -logf(-l1);
}

// ---------------------------------------------------------------------------
// Per-batch sampling: one block per row. (unchanged, verified round 2)
// ---------------------------------------------------------------------------
#define NBINS 4096
#define CAP   2048
#define NKEEP 64

__global__ __launch_bounds__(256) void sample_kernel(
    const float* __restrict__ logits,  // [B][V] scaled
    const float* __restrict__ top_ps,  // [B]
    const int*   __restrict__ top_ks,  // [B]
    int*         __restrict__ out_ids, // [B]
    int V)
{
    const int b = blockIdx.x;
    const int tid = threadIdx.x;
    const float* row = logits + (size_t)b * V;

    __shared__ float swred[4];
    __shared__ int   bins[NBINS];
    __shared__ int   schunk[256];
    __shared__ int   sThrBin, sCnt, sMkeep;
    __shared__ float cval[CAP];
    __shared__ int   cidx[CAP];
    __shared__ float tval[NKEEP];
    __shared__ int   tidxs[NKEEP];

    // ---- pass 1: row max ----
    float m = -INFINITY;
    for (int k = tid; k < V; k += 256) m = fmaxf(m, row[k]);
#pragma unroll
    for (int o = 32; o > 0; o >>= 1) m = fmaxf(m, __shfl_xor(m, o, 64));
    if ((tid & 63) == 0) swred[tid >> 6] = m;
    __syncthreads();
    m = fmaxf(fmaxf(swred[0], swred[1]), fmaxf(swred[2], swred[3]));

    // ---- zero histogram ----
    for (int k = tid; k < NBINS; k += 256) bins[k] = 0;
    if (tid == 0) sCnt = 0;
    __syncthreads();

    // ---- pass 2: sum(exp(x-m)) + histogram of g = m - x ----
    float s = 0.f;
    for (int k = tid; k < V; k += 256) {
        const float x = row[k];
        s += expf(x - m);
        const float g = m - x;
        int bin = (int)(g * 256.0f);
        if (bin >= NBINS) bin = NBINS - 1;
        atomicAdd(&bins[bin], 1);
    }
#pragma unroll
    for (int o = 32; o > 0; o >>= 1) s += __shfl_xor(s, o, 64);
    __syncthreads();
    if ((tid & 63) == 0) swred[tid >> 6] = s;

    int csum = 0;
#pragma unroll
    for (int k = 0; k < NBINS / 256; ++k) csum += bins[tid * (NBINS / 256) + k];
    schunk[tid] = csum;
    __syncthreads();
    s = swred[0] + swred[1] + swred[2] + swred[3];
    if (tid == 0) {
        int cum = 0, chunk = 255;
        for (int c = 0; c < 256; ++c) {
            if (cum + schunk[c] >= NKEEP) { chunk = c; break; }
            cum += schunk[c];
        }
        int t = NBINS - 1;
        const int base = chunk * (NBINS / 256);
        for (int k = base; k < base + NBINS / 256; ++k) {
            cum += bins[k];
            if (cum >= NKEEP) { t = k; break; }
        }
        sThrBin = t;
    }
    __syncthreads();
    const int thrBin = sThrBin;

    // ---- pass 3: compact candidates ----
    for (int k = tid; k < V; k += 256) {
        const float x = row[k];
        const float g = m - x;
        int bin = (int)(g * 256.0f);
        if (bin >= NBINS) bin = NBINS - 1;
        if (bin <= thrBin) {
            const int p = atomicAdd(&sCnt, 1);
            if (p < CAP) { cval[p] = x; cidx[p] = k; }
        }
    }
    __syncthreads();
    const int C = min(sCnt, CAP);

    // ---- pass 4: rank-select top NKEEP ----
    for (int i = tid; i < C; i += 256) {
        const float vi = cval[i];
        const int   ii = cidx[i];
        int rank = 0;
        for (int j = 0; j < C; ++j) {
            const float vj = cval[j];
            const int   ij = cidx[j];
            rank += (vj > vi) || (vj == vi && ij < ii);
        }
        if (rank < NKEEP) { tval[rank] = vi; tidxs[rank] = ii; }
    }
    __syncthreads();

    // ---- pass 5: serial top-p/top-k cut ----
    if (tid == 0) {
        const float pb = top_ps[b];
        const int   kk = top_ks[b];
        const int   nk = min(NKEEP, C);
        float cum = 0.f;
        int mk = 0;
        for (int r = 0; r < nk; ++r) {
            const float pr = expf(tval[r] - m) / s;
            cum += pr;
            const float excl = cum - pr;
            if (excl > pb || r >= kk) break;
            ++mk;
        }
        sMkeep = (mk > 0) ? mk : 1;
    }
    __syncthreads();
    const int mkeep = sMkeep;

    // ---- pass 6: gumbel argmax over kept prefix ----
    if (tid < 64) {
        float sc = -INFINITY;
        int vid = INT_MAX;
        if (tid < mkeep) {
            const int v = tidxs[tid];
            vid = v;
            sc = tval[tid] + jax_gumbel((uint32_t)b * (uint32_t)V + (uint32_t)v);
        }
#pragma unroll
        for (int o = 32; o > 0; o >>= 1) {
            const float os = __shfl_xor(sc, o, 64);
            const int   ov = __shfl_xor(vid, o, 64);
            if (os > sc || (os == sc && ov < vid)) { sc = os; vid = ov; }
        }
        if (tid == 0) out_ids[b] = vid;
    }
}

extern "C" void kernel_launch(void* const* d_in, const int* in_sizes, int n_in,
                              void* d_out, int out_size, void* d_ws, size_t ws_size,
                              hipStream_t stream)
{
    const float* emb   = (const float*)d_in[0];
    const float* hs    = (const float*)d_in[1];
    const int*   pos   = (const int*)d_in[2];
    const float* temps = (const float*)d_in[3];
    const float* tps   = (const float*)d_in[4];
    const int*   tks   = (const int*)d_in[5];
    const float* bias  = (const float*)d_in[6];

    const int B = in_sizes[3];                     // temperatures
    const int V = in_sizes[6];                     // bias
    const int H = (int)((long long)in_sizes[0] / V);
    const int L = (int)((long long)in_sizes[1] / ((long long)B * H));

    float*          logits = (float*)d_ws;                        // B*V fp32
    unsigned short* Ahi    = (unsigned short*)((char*)d_ws + (16u << 20));
    unsigned short* Alo    = Ahi + (size_t)B * H;                 // 512 KB each

    prep_h<<<(B * H) / (16 * 256), 256, 0, stream>>>(hs, pos, Ahi, Alo, H, L);

    const int nblk = (V + 127) / 128;
    logits_mfma<<<nblk, 256, 0, stream>>>(emb, Ahi, Alo, temps, bias,
                                          logits, V, H);

    sample_kernel<<<B, 256, 0, stream>>>(logits, tps, tks, (int*)d_out, V);
}